// Round 2
// baseline (357.252 us; speedup 1.0000x reference)
//
#include <hip/hip_runtime.h>

typedef unsigned short u16;
typedef __attribute__((ext_vector_type(8))) u16 u16x8;
typedef __attribute__((ext_vector_type(8))) __bf16 bf16x8;
typedef __attribute__((ext_vector_type(4))) float f32x4;

// d_out layout (floats): coefs | alpha | new_state | new_buf
#define ALPHA_OFF   3932160
#define NST_OFF     3936256
#define NBUF_OFF    6033408

__device__ __forceinline__ u16 f2bf(float f) {
  unsigned u = __builtin_bit_cast(unsigned, f);
  u += 0x7fffu + ((u >> 16) & 1u);
  return (u16)(u >> 16);
}
__device__ __forceinline__ float bf2f(u16 v) {
  return __builtin_bit_cast(float, (unsigned)v << 16);
}
__device__ __forceinline__ float fsig(float x) { return 1.f / (1.f + __expf(-x)); }
__device__ __forceinline__ float ftanh(float x) {
  x = fminf(15.f, fmaxf(-15.f, x));
  float e = __expf(2.f * x);
  return (e - 1.f) / (e + 1.f);
}
__device__ __forceinline__ f32x4 mfma16(u16x8 a, u16x8 b, f32x4 c) {
  return __builtin_amdgcn_mfma_f32_16x16x32_bf16(
      __builtin_bit_cast(bf16x8, a), __builtin_bit_cast(bf16x8, b), c, 0, 0, 0);
}
__device__ __forceinline__ void gload16(const void* g, void* l) {
  __builtin_amdgcn_global_load_lds(
      (const __attribute__((address_space(1))) void*)g,
      (__attribute__((address_space(3))) void*)l, 16, 0, 0);
}

// ---- K0: W2[L][768][512] bf16 = transpose(concat(gk, grk, axis=0)) --------
__global__ __launch_bounds__(256) void wprep_kernel(
    const float* __restrict__ gk0, const float* __restrict__ grk0,
    const float* __restrict__ gk1, const float* __restrict__ grk1,
    u16* __restrict__ W2) {
  __shared__ u16 tl[64][65];
  int nb = blockIdx.x, kb = blockIdx.y, L = blockIdx.z;
  const float* src = (kb < 4) ? (L ? gk1 : gk0) : (L ? grk1 : grk0);
  int kbase = (kb & 3) * 64;
  u16* dst = W2 + (size_t)L * 768 * 512;
  int tid = threadIdx.x, c = tid & 63, r4 = tid >> 6;
  for (int rr = 0; rr < 64; rr += 4) {
    int k = kbase + rr + r4, n = nb * 64 + c;
    tl[rr + r4][c] = f2bf(src[(size_t)k * 768 + n]);      // coalesced along n
  }
  __syncthreads();
  for (int rr = 0; rr < 64; rr += 4) {
    int n = nb * 64 + rr + r4, k = kb * 64 + c;
    dst[(size_t)n * 512 + k] = tl[c][rr + r4];            // coalesced along k
  }
}

// ---- K1: A0 = [relu(grouped(emb,w_in)) | h0]bf16 ; A1[:,256:] = h1 --------
__global__ __launch_bounds__(256) void prep_kernel(
    const float* __restrict__ emb, const float* __restrict__ dec,
    const float* __restrict__ w_in, u16* __restrict__ A0, u16* __restrict__ A1) {
  __shared__ float wl[8192];       // w_in [g][i][o]
  __shared__ float el[16][256];
  int tid = threadIdx.x, rowBase = blockIdx.x * 16;
  for (int i = tid; i < 8192; i += 256) wl[i] = w_in[i];
  for (int i = tid; i < 4096; i += 256)
    el[i >> 8][i & 255] = emb[(size_t)(rowBase + (i >> 8)) * 256 + (i & 255)];
  __syncthreads();
  int g = tid >> 5, o = tid & 31;
  for (int r = 0; r < 16; ++r) {
    float acc = 0.f;
#pragma unroll
    for (int i = 0; i < 32; ++i) acc += el[r][g * 32 + i] * wl[g * 1024 + i * 32 + o];
    A0[(size_t)(rowBase + r) * 512 + tid] = f2bf(fmaxf(acc, 0.f));
  }
  for (int i = tid; i < 8192; i += 256) {
    int r = i >> 9, c = i & 511;
    u16 q = f2bf(dec[(size_t)(rowBase + r) * 512 + c]);
    if (c < 256) A0[(size_t)(rowBase + r) * 512 + 256 + c] = q;
    else         A1[(size_t)(rowBase + r) * 512 + c] = q;
  }
}

// ---- K2/K3: GRU layer as MFMA GEMM, fused gate epilogue -------------------
// M=4096 K=512(x|h) ; B^T = W2[768][512]: n<256 z, n<512 r, n<768 h-gate
// (h-gate cols accumulate xh for k<256, hh for k>=256).
// Block: 64 rows x 64 cols-per-gate; 4 waves, each 16 cols of all gates.
template <int LAYER>
__global__ __launch_bounds__(256) void gru_kernel(
    const u16* __restrict__ Ain,    // [4096][512] bf16
    const u16* __restrict__ W2,     // [768][512] bf16
    const float* __restrict__ dec,
    const float* __restrict__ bias, // [2][768]
    float* __restrict__ nst,        // d_out+NST_OFF [4096][512]
    u16* __restrict__ a1out,        // LAYER0: A1 (write cols 0-255)
    const u16* __restrict__ xbf,    // LAYER1: A0 (x in cols 0-255)
    float* __restrict__ c_f32) {    // LAYER1
  __shared__ __align__(16) u16 lsA[2][64][32];
  __shared__ __align__(16) u16 lsB[2][3][64][32];
  int tid = threadIdx.x, lane = tid & 63, wave = tid >> 6;
  int m0 = lane & 15, quad = lane >> 4;
  int rowBase = blockIdx.x * 64, jz = blockIdx.y * 64, cw = wave * 16;
  f32x4 acc[4][4];
#pragma unroll
  for (int gi = 0; gi < 4; ++gi)
#pragma unroll
    for (int rb = 0; rb < 4; ++rb) acc[gi][rb] = (f32x4){0.f, 0.f, 0.f, 0.f};

  int rS = tid >> 2, qS = tid & 3;  // staging chunk: row 0..63, 8-elem quad
  auto stage = [&](int buf, int k0) {
    gload16(Ain + (size_t)(rowBase + rS) * 512 + k0 + qS * 8, &lsA[buf][rS][qS * 8]);
#pragma unroll
    for (int g = 0; g < 3; ++g)
      gload16(W2 + (size_t)(g * 256 + jz + rS) * 512 + k0 + qS * 8,
              &lsB[buf][g][rS][qS * 8]);
  };

  stage(0, 0);
  for (int step = 0; step < 16; ++step) {
    __syncthreads();
    if (step < 15) stage((step & 1) ^ 1, (step + 1) * 32);
    int cur = step & 1;
    u16x8 av[4], bv[3];
#pragma unroll
    for (int rb = 0; rb < 4; ++rb)
      av[rb] = *(const u16x8*)&lsA[cur][rb * 16 + m0][quad * 8];
#pragma unroll
    for (int g = 0; g < 3; ++g)
      bv[g] = *(const u16x8*)&lsB[cur][g][cw + m0][quad * 8];
#pragma unroll
    for (int rb = 0; rb < 4; ++rb) {
      acc[0][rb] = mfma16(av[rb], bv[0], acc[0][rb]);
      acc[1][rb] = mfma16(av[rb], bv[1], acc[1][rb]);
    }
    if (step < 8) {
#pragma unroll
      for (int rb = 0; rb < 4; ++rb) acc[2][rb] = mfma16(av[rb], bv[2], acc[2][rb]);
    } else {
#pragma unroll
      for (int rb = 0; rb < 4; ++rb) acc[3][rb] = mfma16(av[rb], bv[2], acc[3][rb]);
    }
  }

  int col = jz + cw + m0;                       // [0,256) within gate
  float bz = bias[col] + bias[768 + col];
  float br = bias[256 + col] + bias[1024 + col];
  float bxh = bias[512 + col];
  float bhh = bias[1280 + col];
  const int hoff = LAYER ? 256 : 0;
#pragma unroll
  for (int rb = 0; rb < 4; ++rb) {
#pragma unroll
    for (int i = 0; i < 4; ++i) {
      int row = rowBase + rb * 16 + quad * 4 + i;  // C/D: col=lane&15,row=quad*4+reg
      float h = dec[(size_t)row * 512 + hoff + col];
      float z = fsig(acc[0][rb][i] + bz);
      float r = fsig(acc[1][rb][i] + br);
      float cand = ftanh(acc[2][rb][i] + bxh + r * (acc[3][rb][i] + bhh));
      float o = z * h + (1.f - z) * cand;
      nst[(size_t)row * 512 + hoff + col] = o;
      if (LAYER == 0) {
        a1out[(size_t)row * 512 + col] = f2bf(o);
      } else {
        float c = o + bf2f(xbf[(size_t)row * 512 + col]);
        c_f32[(size_t)row * 256 + col] = c;
      }
    }
  }
}

// ---- K4: tanh(grouped(c,w_out)) -> flat temp in coefs region --------------
__global__ __launch_bounds__(256) void wout_kernel(
    const float* __restrict__ c_f32, const float* __restrict__ w_out,
    float* __restrict__ outc) {
  __shared__ float cs[16][256];
  int tid = threadIdx.x, rowBase = blockIdx.x * 16;
  for (int i = tid; i < 4096; i += 256)
    cs[i >> 8][i & 255] = c_f32[(size_t)(rowBase + (i >> 8)) * 256 + (i & 255)];
  __syncthreads();
  for (int flat = tid; flat < 960; flat += 256) {
    int g = flat / 120, og = flat % 120;
    float acc[16];
#pragma unroll
    for (int r = 0; r < 16; ++r) acc[r] = 0.f;
    for (int i = 0; i < 32; ++i) {
      float w = w_out[(size_t)g * 3840 + i * 120 + og];
#pragma unroll
      for (int r = 0; r < 16; ++r) acc[r] += cs[r][g * 32 + i] * w;
    }
#pragma unroll
    for (int r = 0; r < 16; ++r)
      outc[(size_t)(rowBase + r) * 960 + flat] = ftanh(acc[r]);
  }
}

// ---- K5: conv+pw+BN+relu + combine + alpha + new_buf, 1 row/block ---------
__global__ __launch_bounds__(256) void head_kernel(
    const float* __restrict__ convp, const float* __restrict__ c0,
    const float* __restrict__ c_f32,
    const float* __restrict__ conv_w, const float* __restrict__ pw_w,
    const float* __restrict__ bng, const float* __restrict__ bnb,
    const float* __restrict__ bnm, const float* __restrict__ bnv,
    const float* __restrict__ fca_w, const float* __restrict__ fca_b,
    float* __restrict__ outp) {
  __shared__ __align__(16) u16 xs[5 * 96 * 16];   // bf16 staged x
  __shared__ float ybuf[96][10];
  __shared__ float cw[400];
  __shared__ float pw[100];
  __shared__ float bscale[10], bshift[10];
  __shared__ float ared[4];
  int tid = threadIdx.x, lane = tid & 63, wave = tid >> 6;
  int b = blockIdx.x;
  for (int i = tid; i < 400; i += 256) cw[i] = conv_w[i];
  if (tid < 100) pw[tid] = pw_w[tid];
  if (tid < 10) {
    float s = bng[tid] * rsqrtf(bnv[tid] + 1e-3f);
    bscale[tid] = s;
    bshift[tid] = bnb[tid] - bnm[tid] * s;
  }
  float4* nb4 = (float4*)(outp + NBUF_OFF);
  const float4* cp4 = (const float4*)convp;
  const float4* c04 = (const float4*)c0;

  // stage x = [convp | c0] (bf16 into LDS); new_buf write shares the read
  for (int i = tid; i < 1920; i += 256) {
    int t = i / 384, p = i % 384;
    float4 v = (t < 4) ? cp4[(size_t)b * 1536 + i] : c04[(size_t)b * 384 + p];
    if (t >= 1) nb4[(size_t)b * 1536 + (size_t)(t - 1) * 384 + p] = v;
    ushort4 q;
    q.x = f2bf(v.x); q.y = f2bf(v.y); q.z = f2bf(v.z); q.w = f2bf(v.w);
    ((ushort4*)xs)[i] = q;
  }
  // alpha partials (global reads, independent of LDS)
  float ap = c_f32[(size_t)b * 256 + tid] * fca_w[tid];
#pragma unroll
  for (int off = 32; off > 0; off >>= 1) ap += __shfl_down(ap, off, 64);
  if (lane == 0) ared[wave] = ap;
  __syncthreads();
  if (tid == 0)
    outp[ALPHA_OFF + b] = fsig(ared[0] + ared[1] + ared[2] + ared[3] + fca_b[0]);
  // grouped depth conv: thread=(f,half), b128 LDS reads
  if (tid < 192) {
    int f = tid >> 1, half = tid & 1;
    float a5[5] = {0.f, 0.f, 0.f, 0.f, 0.f};
#pragma unroll
    for (int t = 0; t < 5; ++t) {
      u16x8 xv = *(const u16x8*)&xs[t * 1536 + f * 16 + half * 8];
#pragma unroll
      for (int i = 0; i < 8; ++i) {
        float xf = bf2f(xv[i]);
#pragma unroll
        for (int j = 0; j < 5; ++j)
          a5[j] += xf * cw[t * 80 + i * 10 + half * 5 + j];
      }
    }
#pragma unroll
    for (int j = 0; j < 5; ++j) ybuf[f][half * 5 + j] = a5[j];
  }
  __syncthreads();
  // pw + BN + relu + add tanh-term (flat temp), then rewrite in coefs order
  float vals[4];
  int nv = 0;
  for (int u2 = tid; u2 < 480; u2 += 256) {
    int o = u2 / 96, f = u2 % 96;
#pragma unroll
    for (int q = 0; q < 2; ++q) {
      int p = o * 2 + q;
      float y2 = 0.f;
#pragma unroll
      for (int j = 0; j < 10; ++j) y2 += ybuf[f][j] * pw[j * 10 + p];
      float bnr = fmaxf(y2 * bscale[p] + bshift[p], 0.f);
      float wt = outp[(size_t)b * 960 + f * 10 + p];   // flat temp from wout
      vals[nv++] = bnr + wt;
    }
  }
  __syncthreads();   // all flat-temp reads done before overwrite
  nv = 0;
  for (int u2 = tid; u2 < 480; u2 += 256) {
    int o = u2 / 96, f = u2 % 96;
    *(float2*)&outp[(size_t)b * 960 + o * 192 + f * 2] =
        make_float2(vals[nv], vals[nv + 1]);
    nv += 2;
  }
}

// ---------------------------------------------------------------------------
extern "C" void kernel_launch(void* const* d_in, const int* in_sizes, int n_in,
                              void* d_out, int out_size, void* d_ws, size_t ws_size,
                              hipStream_t stream) {
  const float* emb    = (const float*)d_in[0];
  const float* c0     = (const float*)d_in[1];
  const float* dec    = (const float*)d_in[2];
  const float* convp  = (const float*)d_in[3];
  const float* w_in   = (const float*)d_in[4];
  const float* gk0    = (const float*)d_in[5];
  const float* grk0   = (const float*)d_in[6];
  const float* gb0    = (const float*)d_in[7];
  const float* gk1    = (const float*)d_in[8];
  const float* grk1   = (const float*)d_in[9];
  const float* gb1    = (const float*)d_in[10];
  const float* w_out  = (const float*)d_in[11];
  const float* fca_w  = (const float*)d_in[12];
  const float* fca_b  = (const float*)d_in[13];
  const float* conv_w = (const float*)d_in[14];
  const float* pw_w   = (const float*)d_in[15];
  const float* bng    = (const float*)d_in[16];
  const float* bnb    = (const float*)d_in[17];
  const float* bnm    = (const float*)d_in[18];
  const float* bnv    = (const float*)d_in[19];
  float* out = (float*)d_out;
  char* ws = (char*)d_ws;
  u16*   A0    = (u16*)(ws + 0);           // [4096][512] bf16, 4 MB
  u16*   A1    = (u16*)(ws + 4194304);     // [4096][512] bf16, 4 MB
  float* c_f32 = (float*)(ws + 8388608);   // [4096][256] f32, 4 MB
  u16*   W2    = (u16*)(ws + 12582912);    // [2][768][512] bf16, 1.5 MB

  wprep_kernel<<<dim3(12, 8, 2), 256, 0, stream>>>(gk0, grk0, gk1, grk1, W2);
  prep_kernel<<<dim3(256), 256, 0, stream>>>(emb, dec, w_in, A0, A1);
  gru_kernel<0><<<dim3(64, 4), 256, 0, stream>>>(A0, W2, dec, gb0,
                                                 out + NST_OFF, A1, nullptr, nullptr);
  gru_kernel<1><<<dim3(64, 4), 256, 0, stream>>>(A1, W2 + 768 * 512, dec, gb1,
                                                 out + NST_OFF, nullptr, A0, c_f32);
  wout_kernel<<<dim3(256), 256, 0, stream>>>(c_f32, w_out, out);
  head_kernel<<<dim3(4096), 256, 0, stream>>>(convp, c0, c_f32, conv_w, pw_w,
                                              bng, bnb, bnm, bnv, fca_w, fca_b, out);
}

// Round 3
// 313.878 us; speedup vs baseline: 1.1382x; 1.1382x over previous
//
#include <hip/hip_runtime.h>

typedef unsigned short u16;
typedef __attribute__((ext_vector_type(8))) u16 u16x8;
typedef __attribute__((ext_vector_type(8))) __bf16 bf16x8;
typedef __attribute__((ext_vector_type(4))) float f32x4;

// d_out layout (floats): coefs | alpha | new_state | new_buf
#define ALPHA_OFF   3932160
#define NST_OFF     3936256
#define NBUF_OFF    6033408

__device__ __forceinline__ u16 f2bf(float f) {
  unsigned u = __builtin_bit_cast(unsigned, f);
  u += 0x7fffu + ((u >> 16) & 1u);
  return (u16)(u >> 16);
}
__device__ __forceinline__ float bf2f(u16 v) {
  return __builtin_bit_cast(float, (unsigned)v << 16);
}
__device__ __forceinline__ float fsig(float x) { return 1.f / (1.f + __expf(-x)); }
__device__ __forceinline__ float ftanh(float x) {
  x = fminf(15.f, fmaxf(-15.f, x));
  float e = __expf(2.f * x);
  return (e - 1.f) / (e + 1.f);
}
__device__ __forceinline__ f32x4 mfma16(u16x8 a, u16x8 b, f32x4 c) {
  return __builtin_amdgcn_mfma_f32_16x16x32_bf16(
      __builtin_bit_cast(bf16x8, a), __builtin_bit_cast(bf16x8, b), c, 0, 0, 0);
}
__device__ __forceinline__ void gload16(const void* g, void* l) {
  __builtin_amdgcn_global_load_lds(
      (const __attribute__((address_space(1))) void*)g,
      (__attribute__((address_space(3))) void*)l, 16, 0, 0);
}

// ---- K0: W2[L][768][512] bf16 = transpose(concat(gk, grk, axis=0)) --------
__global__ __launch_bounds__(256) void wprep_kernel(
    const float* __restrict__ gk0, const float* __restrict__ grk0,
    const float* __restrict__ gk1, const float* __restrict__ grk1,
    u16* __restrict__ W2) {
  __shared__ u16 tl[64][65];
  int nb = blockIdx.x, kb = blockIdx.y, L = blockIdx.z;
  const float* src = (kb < 4) ? (L ? gk1 : gk0) : (L ? grk1 : grk0);
  int kbase = (kb & 3) * 64;
  u16* dst = W2 + (size_t)L * 768 * 512;
  int tid = threadIdx.x, c = tid & 63, r4 = tid >> 6;
  for (int rr = 0; rr < 64; rr += 4) {
    int k = kbase + rr + r4, n = nb * 64 + c;
    tl[rr + r4][c] = f2bf(src[(size_t)k * 768 + n]);      // coalesced along n
  }
  __syncthreads();
  for (int rr = 0; rr < 64; rr += 4) {
    int n = nb * 64 + rr + r4, k = kb * 64 + c;
    dst[(size_t)n * 512 + k] = tl[c][rr + r4];            // coalesced along k
  }
}

// ---- K0b: W3[8][128][32] bf16 = w_out[g][k][col] transposed, zero-pad -----
__global__ __launch_bounds__(256) void w3prep_kernel(
    const float* __restrict__ w_out, u16* __restrict__ W3) {
  int g = blockIdx.x, tid = threadIdx.x;
  for (int i = tid; i < 4096; i += 256) {
    int col = i >> 5, k = i & 31;
    float v = (col < 120) ? w_out[(size_t)g * 3840 + k * 120 + col] : 0.f;
    W3[(size_t)g * 4096 + i] = f2bf(v);
  }
}

// ---- K1: A0 = [relu(grouped(emb,w_in)) | h0]bf16 ; A1[:,256:] = h1 --------
// 4 rows/block, weights in registers (L2-hot re-read), grid 1024.
__global__ __launch_bounds__(256) void prep_kernel(
    const float* __restrict__ emb, const float* __restrict__ dec,
    const float* __restrict__ w_in, u16* __restrict__ A0, u16* __restrict__ A1) {
  __shared__ float el[4][256];
  int tid = threadIdx.x, rowBase = blockIdx.x * 4;
  {
    int r = tid >> 6, c4 = tid & 63;
    *(float4*)&el[r][c4 * 4] = ((const float4*)emb)[(size_t)(rowBase + r) * 64 + c4];
  }
  int g = tid >> 5, o = tid & 31;
  float wr[32];
#pragma unroll
  for (int i = 0; i < 32; ++i) wr[i] = w_in[g * 1024 + i * 32 + o];
  __syncthreads();
#pragma unroll
  for (int r = 0; r < 4; ++r) {
    float acc = 0.f;
#pragma unroll
    for (int i = 0; i < 32; ++i) acc += el[r][g * 32 + i] * wr[i];
    A0[(size_t)(rowBase + r) * 512 + tid] = f2bf(fmaxf(acc, 0.f));
  }
  const float4* d4 = (const float4*)dec;
#pragma unroll
  for (int j = 0; j < 2; ++j) {
    int idx = tid + j * 256;                 // 512 float4 = 4 rows x 128
    int r = idx >> 7, c4 = idx & 127;
    float4 v = d4[(size_t)(rowBase + r) * 128 + c4];
    ushort4 q;
    q.x = f2bf(v.x); q.y = f2bf(v.y); q.z = f2bf(v.z); q.w = f2bf(v.w);
    u16* dst = (c4 < 64) ? A0 + (size_t)(rowBase + r) * 512 + 256 + c4 * 4
                         : A1 + (size_t)(rowBase + r) * 512 + 256 + (c4 - 64) * 4;
    *(ushort4*)dst = q;
  }
}

// ---- K2/K3: GRU layer as MFMA GEMM, fused gate epilogue -------------------
// 32 rows x 64 cols/gate per block; grid (128,4) = 512 blocks = 2/CU.
template <int LAYER>
__global__ __launch_bounds__(256) void gru_kernel(
    const u16* __restrict__ Ain,    // [4096][512] bf16
    const u16* __restrict__ W2,     // [768][512] bf16
    const float* __restrict__ dec,
    const float* __restrict__ bias, // [2][768]
    float* __restrict__ nst,        // d_out+NST_OFF [4096][512]
    u16* __restrict__ a1out,        // LAYER0: A1 cols 0-255
    const u16* __restrict__ xbf,    // LAYER1: A0 (x in cols 0-255)
    u16* __restrict__ c_bf) {       // LAYER1: [4096][256] bf16
  __shared__ __align__(16) u16 lsA[2][32][32];
  __shared__ __align__(16) u16 lsB[2][3][64][32];
  int tid = threadIdx.x, lane = tid & 63, wave = tid >> 6;
  int m0 = lane & 15, quad = lane >> 4;
  int rowBase = blockIdx.x * 32, jz = blockIdx.y * 64, cw = wave * 16;
  f32x4 acc[4][2];
#pragma unroll
  for (int gi = 0; gi < 4; ++gi)
#pragma unroll
    for (int rb = 0; rb < 2; ++rb) acc[gi][rb] = (f32x4){0.f, 0.f, 0.f, 0.f};

  int rS = tid >> 2, qS = tid & 3;
  auto stage = [&](int buf, int k0) {
    if (tid < 128)
      gload16(Ain + (size_t)(rowBase + rS) * 512 + k0 + qS * 8,
              &lsA[buf][rS][qS * 8]);
#pragma unroll
    for (int g = 0; g < 3; ++g)
      gload16(W2 + (size_t)(g * 256 + jz + rS) * 512 + k0 + qS * 8,
              &lsB[buf][g][rS][qS * 8]);
  };

  stage(0, 0);
  for (int step = 0; step < 16; ++step) {
    __syncthreads();
    if (step < 15) stage((step & 1) ^ 1, (step + 1) * 32);
    int cur = step & 1;
    u16x8 av[2], bv[3];
#pragma unroll
    for (int rb = 0; rb < 2; ++rb)
      av[rb] = *(const u16x8*)&lsA[cur][rb * 16 + m0][quad * 8];
#pragma unroll
    for (int g = 0; g < 3; ++g)
      bv[g] = *(const u16x8*)&lsB[cur][g][cw + m0][quad * 8];
#pragma unroll
    for (int rb = 0; rb < 2; ++rb) {
      acc[0][rb] = mfma16(av[rb], bv[0], acc[0][rb]);
      acc[1][rb] = mfma16(av[rb], bv[1], acc[1][rb]);
    }
    if (step < 8) {
#pragma unroll
      for (int rb = 0; rb < 2; ++rb) acc[2][rb] = mfma16(av[rb], bv[2], acc[2][rb]);
    } else {
#pragma unroll
      for (int rb = 0; rb < 2; ++rb) acc[3][rb] = mfma16(av[rb], bv[2], acc[3][rb]);
    }
  }

  int col = jz + cw + m0;
  float bz = bias[col] + bias[768 + col];
  float br = bias[256 + col] + bias[1024 + col];
  float bxh = bias[512 + col];
  float bhh = bias[1280 + col];
  const int hoff = LAYER ? 256 : 0;
#pragma unroll
  for (int rb = 0; rb < 2; ++rb) {
#pragma unroll
    for (int i = 0; i < 4; ++i) {
      int row = rowBase + rb * 16 + quad * 4 + i;  // C/D: col=lane&15,row=quad*4+reg
      float h = dec[(size_t)row * 512 + hoff + col];
      float z = fsig(acc[0][rb][i] + bz);
      float r = fsig(acc[1][rb][i] + br);
      float cand = ftanh(acc[2][rb][i] + bxh + r * (acc[3][rb][i] + bhh));
      float o = z * h + (1.f - z) * cand;
      nst[(size_t)row * 512 + hoff + col] = o;
      if (LAYER == 0) {
        a1out[(size_t)row * 512 + col] = f2bf(o);
      } else {
        float c = o + bf2f(xbf[(size_t)row * 512 + col]);
        c_bf[(size_t)row * 256 + col] = f2bf(c);
      }
    }
  }
}

// ---- K4: flat temp = tanh(grouped(c,w_out)) via MFMA (K=32, one step) -----
// Block: 64 rows x 1 group (128 cols, 120 live). Grid (64, 8).
__global__ __launch_bounds__(256) void wout_kernel(
    const u16* __restrict__ c_bf, const u16* __restrict__ W3,
    float* __restrict__ outc) {
  __shared__ __align__(16) u16 lsA[64][32];
  __shared__ __align__(16) u16 lsB[128][32];
  int tid = threadIdx.x, lane = tid & 63, wave = tid >> 6;
  int m0 = lane & 15, quad = lane >> 4;
  int rowBase = blockIdx.x * 64, g = blockIdx.y;
  {
    int r = tid >> 2, q = tid & 3;
    gload16(c_bf + (size_t)(rowBase + r) * 256 + g * 32 + q * 8, &lsA[r][q * 8]);
    gload16(W3 + (size_t)g * 4096 + (size_t)r * 32 + q * 8, &lsB[r][q * 8]);
    gload16(W3 + (size_t)g * 4096 + (size_t)(64 + r) * 32 + q * 8, &lsB[64 + r][q * 8]);
  }
  __syncthreads();
  int cw = wave * 32;
  f32x4 acc[4][2];
#pragma unroll
  for (int rb = 0; rb < 4; ++rb)
#pragma unroll
    for (int cb = 0; cb < 2; ++cb) acc[rb][cb] = (f32x4){0.f, 0.f, 0.f, 0.f};
  u16x8 bv[2];
#pragma unroll
  for (int cb = 0; cb < 2; ++cb)
    bv[cb] = *(const u16x8*)&lsB[cw + cb * 16 + m0][quad * 8];
#pragma unroll
  for (int rb = 0; rb < 4; ++rb) {
    u16x8 av = *(const u16x8*)&lsA[rb * 16 + m0][quad * 8];
#pragma unroll
    for (int cb = 0; cb < 2; ++cb) acc[rb][cb] = mfma16(av, bv[cb], acc[rb][cb]);
  }
#pragma unroll
  for (int cb = 0; cb < 2; ++cb) {
    int cg = cw + cb * 16 + m0;
    if (cg < 120) {
#pragma unroll
      for (int rb = 0; rb < 4; ++rb)
#pragma unroll
        for (int i = 0; i < 4; ++i)
          outc[(size_t)(rowBase + rb * 16 + quad * 4 + i) * 960 + g * 120 + cg] =
              ftanh(acc[rb][cb][i]);
    }
  }
}

// ---- K5: conv+pw+BN+relu + combine + alpha + new_buf ----------------------
// 1 row/block, 192 threads; conv input partitions exactly over (f,half):
// no LDS staging, all global loads issued up front.
__global__ __launch_bounds__(192) void head_kernel(
    const float* __restrict__ convp, const float* __restrict__ c0,
    const u16* __restrict__ c_bf,
    const float* __restrict__ conv_w, const float* __restrict__ pw_w,
    const float* __restrict__ bng, const float* __restrict__ bnb,
    const float* __restrict__ bnm, const float* __restrict__ bnv,
    const float* __restrict__ fca_w, const float* __restrict__ fca_b,
    float* __restrict__ outp) {
  __shared__ float cw[400];
  __shared__ float pws[100];
  __shared__ float bsc[10], bsh[10];
  __shared__ float ybuf[96][11];
  __shared__ float ared[3];
  int tid = threadIdx.x, lane = tid & 63, wave = tid >> 6;
  int b = blockIdx.x;
  int f = tid >> 1, half = tid & 1;
  const float4* cp4 = (const float4*)convp;
  const float4* c04 = (const float4*)c0;
  float4* nb4 = (float4*)(outp + NBUF_OFF);

  // ---- front-issue all global reads ----
  float4 xa[5], xb[5];
#pragma unroll
  for (int t = 0; t < 4; ++t) {
    size_t idx = (size_t)b * 1536 + t * 384 + f * 4 + half * 2;
    xa[t] = cp4[idx]; xb[t] = cp4[idx + 1];
  }
  {
    size_t idx = (size_t)b * 384 + f * 4 + half * 2;
    xa[4] = c04[idx]; xb[4] = c04[idx + 1];
  }
  float tmp[5];
#pragma unroll
  for (int k = 0; k < 5; ++k) {
    int u = tid + k * 192;
    tmp[k] = outp[(size_t)b * 960 + (u % 96) * 10 + (u / 96)];
  }
  float ap = bf2f(c_bf[(size_t)b * 256 + tid]) * fca_w[tid];
  if (tid < 64) ap += bf2f(c_bf[(size_t)b * 256 + 192 + tid]) * fca_w[192 + tid];

  // ---- constants to LDS ----
  for (int i = tid; i < 400; i += 192) cw[i] = conv_w[i];
  if (tid < 100) pws[tid] = pw_w[tid];
  if (tid < 10) {
    float s = bng[tid] * rsqrtf(bnv[tid] + 1e-3f);
    bsc[tid] = s;
    bsh[tid] = bnb[tid] - bnm[tid] * s;
  }
  // ---- new_buf copy from registers ----
#pragma unroll
  for (int t = 1; t < 5; ++t) {
    size_t idx = (size_t)b * 1536 + (t - 1) * 384 + f * 4 + half * 2;
    nb4[idx] = xa[t]; nb4[idx + 1] = xb[t];
  }
  // ---- alpha partial ----
#pragma unroll
  for (int off = 32; off > 0; off >>= 1) ap += __shfl_down(ap, off, 64);
  if (lane == 0) ared[wave] = ap;
  __syncthreads();
  // ---- grouped depth conv (fp32, regs) ----
  float a5[5] = {0.f, 0.f, 0.f, 0.f, 0.f};
#pragma unroll
  for (int t = 0; t < 5; ++t) {
    const float* xr0 = (const float*)&xa[t];
    const float* xr1 = (const float*)&xb[t];
#pragma unroll
    for (int i = 0; i < 8; ++i) {
      float xf = (i < 4) ? xr0[i] : xr1[i - 4];
#pragma unroll
      for (int j = 0; j < 5; ++j)
        a5[j] += xf * cw[t * 80 + i * 10 + half * 5 + j];
    }
  }
#pragma unroll
  for (int j = 0; j < 5; ++j) ybuf[f][half * 5 + j] = a5[j];
  __syncthreads();
  if (tid == 0)
    outp[ALPHA_OFF + b] = fsig(ared[0] + ared[1] + ared[2] + fca_b[0]);
  // ---- pw + BN + relu + add tanh term; write final coefs layout ----
  float vals[5];
#pragma unroll
  for (int k = 0; k < 5; ++k) {
    int u = tid + k * 192;
    int p = u / 96, ff = u % 96;
    float y2 = 0.f;
#pragma unroll
    for (int j = 0; j < 10; ++j) y2 += ybuf[ff][j] * pws[j * 10 + p];
    vals[k] = fmaxf(y2 * bsc[p] + bsh[p], 0.f) + tmp[k];
  }
#pragma unroll
  for (int k = 0; k < 5; ++k) {
    int u = tid + k * 192;
    int p = u / 96, ff = u % 96;
    outp[(size_t)b * 960 + (p >> 1) * 192 + ff * 2 + (p & 1)] = vals[k];
  }
}

// ---------------------------------------------------------------------------
extern "C" void kernel_launch(void* const* d_in, const int* in_sizes, int n_in,
                              void* d_out, int out_size, void* d_ws, size_t ws_size,
                              hipStream_t stream) {
  const float* emb    = (const float*)d_in[0];
  const float* c0     = (const float*)d_in[1];
  const float* dec    = (const float*)d_in[2];
  const float* convp  = (const float*)d_in[3];
  const float* w_in   = (const float*)d_in[4];
  const float* gk0    = (const float*)d_in[5];
  const float* grk0   = (const float*)d_in[6];
  const float* gb0    = (const float*)d_in[7];
  const float* gk1    = (const float*)d_in[8];
  const float* grk1   = (const float*)d_in[9];
  const float* gb1    = (const float*)d_in[10];
  const float* w_out  = (const float*)d_in[11];
  const float* fca_w  = (const float*)d_in[12];
  const float* fca_b  = (const float*)d_in[13];
  const float* conv_w = (const float*)d_in[14];
  const float* pw_w   = (const float*)d_in[15];
  const float* bng    = (const float*)d_in[16];
  const float* bnb    = (const float*)d_in[17];
  const float* bnm    = (const float*)d_in[18];
  const float* bnv    = (const float*)d_in[19];
  float* out = (float*)d_out;
  char* ws = (char*)d_ws;
  u16* A0   = (u16*)(ws + 0);            // [4096][512] bf16, 4 MB
  u16* A1   = (u16*)(ws + 4194304);      // [4096][512] bf16, 4 MB
  u16* c_bf = (u16*)(ws + 8388608);      // [4096][256] bf16, 2 MB
  u16* W2   = (u16*)(ws + 10485760);     // [2][768][512] bf16, 1.5 MB
  u16* W3   = (u16*)(ws + 12058624);     // [8][128][32] bf16, 64 KB

  wprep_kernel<<<dim3(12, 8, 2), 256, 0, stream>>>(gk0, grk0, gk1, grk1, W2);
  w3prep_kernel<<<dim3(8), 256, 0, stream>>>(w_out, W3);
  prep_kernel<<<dim3(1024), 256, 0, stream>>>(emb, dec, w_in, A0, A1);
  gru_kernel<0><<<dim3(128, 4), 256, 0, stream>>>(A0, W2, dec, gb0,
                                                  out + NST_OFF, A1, nullptr, nullptr);
  gru_kernel<1><<<dim3(128, 4), 256, 0, stream>>>(A1, W2 + 768 * 512, dec, gb1,
                                                  out + NST_OFF, nullptr, A0, c_bf);
  wout_kernel<<<dim3(64, 8), 256, 0, stream>>>(c_bf, W3, out);
  head_kernel<<<dim3(4096), 192, 0, stream>>>(convp, c0, c_bf, conv_w, pw_w,
                                              bng, bnb, bnm, bnv, fca_w, fca_b, out);
}